// Round 7
// baseline (311.962 us; speedup 1.0000x reference)
//
#include <hip/hip_runtime.h>

typedef unsigned short u16;
typedef unsigned int u32;
typedef __attribute__((ext_vector_type(8))) short bf16x8;
typedef __attribute__((ext_vector_type(4))) float f32x4;

#define B_ 4
#define H_ 12
#define N_ 2048
#define D_ 768
#define HD_ 64
#define NTOK (B_ * N_)      /* 8192 */
#define NE   (H_ * 3 * HD_) /* 2304 */

#define BK 64
#define CPITCH 144  /* qkv epilogue LDS C-tile pitch (16B-aligned rows) */

// 1/sqrt(64) * log2(e): Q pre-scale so attention uses exp2 (bare v_exp_f32)
#define QSCALE 0.18033688011112042f

__device__ __forceinline__ u16 f2bf(float f) {
    u32 u = __float_as_uint(f);
    u += 0x7fffu + ((u >> 16) & 1u);
    return (u16)(u >> 16);
}

__device__ __forceinline__ f32x4 mfma16(bf16x8 a, bf16x8 b, f32x4 c) {
    return __builtin_amdgcn_mfma_f32_16x16x32_bf16(a, b, c, 0, 0, 0);
}

// async global->LDS, 16B per lane. LDS dest = wave-uniform base + lane*16.
__device__ __forceinline__ void g2l16(const u16* g, u16* l) {
    __builtin_amdgcn_global_load_lds(
        (const __attribute__((address_space(1))) void*)g,
        (__attribute__((address_space(3))) void*)l, 16, 0, 0);
}

// ---------------- fused f32 -> bf16 conversion (z, Wqkv, Wmsa) ----------------
#define NZ4  (NTOK * D_ / 4)
#define NWQ4 (NE * D_ / 4)
#define NWM4 (D_ * D_ / 4)
__global__ __launch_bounds__(256) void cvt_all(const float* __restrict__ z,
                                               const float* __restrict__ Wq,
                                               const float* __restrict__ Wm,
                                               u16* __restrict__ Xbf,
                                               u16* __restrict__ Wqb,
                                               u16* __restrict__ Wmb) {
    int i = blockIdx.x * blockDim.x + threadIdx.x;
    const float* src;
    u16* dst;
    int j;
    if (i < NZ4) {
        src = z; dst = Xbf; j = i;
    } else if (i < NZ4 + NWQ4) {
        src = Wq; dst = Wqb; j = i - NZ4;
    } else if (i < NZ4 + NWQ4 + NWM4) {
        src = Wm; dst = Wmb; j = i - NZ4 - NWQ4;
    } else {
        return;
    }
    float4 v = ((const float4*)src)[j];
    u32 lo = (u32)f2bf(v.x) | ((u32)f2bf(v.y) << 16);
    u32 hi = (u32)f2bf(v.z) | ((u32)f2bf(v.w) << 16);
    ((uint2*)dst)[j] = make_uint2(lo, hi);
}

// ============ GEMM core v3 (R3 exact): single-barrier dbuf + XCD supertile ==
// R4: 3-deep BK=32 counted-vmcnt pipeline REGRESSED (+23us). R5: setprio in
// the MFMA cluster ~null (-3us GEMM side). Residency (3 blk/CU) + simple
// loop + XCD A-slice locality is the local optimum for this core.
#define GEMM_CORE(Xp, Wp, TM, SMELEMS)                                         \
    __shared__ u16 smem[SMELEMS];                                              \
    u16* ldsA = smem;                 /* [2][TM*BK] */                         \
    u16* ldsB = smem + 2 * (TM) * BK; /* [2][128*BK] */                        \
    const int tid = threadIdx.x;                                               \
    const int wave = tid >> 6, lane = tid & 63;                                \
    const int lrow = lane & 15, quad = lane >> 4;                              \
    const int flat_ = blockIdx.x;                                              \
    const int mbase = (((flat_ & 7) << 4) | ((flat_ >> 3) & 15)) * (TM);       \
    const int nbase = (flat_ >> 7) * 128;                                      \
    const int srow = tid >> 3;      /* 0..31 */                                \
    const int schunk = tid & 7;                                                \
    const int sk = (schunk ^ (srow & 7)) << 3; /* swizzled global k-offset */  \
    const int sdst = srow * BK + schunk * 8;   /* lane-contiguous LDS dest */  \
    const u16* gA = Xp + (size_t)(mbase + srow) * D_ + sk;                     \
    const u16* gB = Wp + (size_t)(nbase + srow) * D_ + sk;                     \
    const int m_ofs = (wave >> 1) * ((TM) / 2);                                \
    const int n_ofs = (wave & 1) * 64;                                         \
    const int e_ = lrow & 7;                                                   \
    const int offA0 = (m_ofs + lrow) * BK + ((quad ^ e_) << 3);                \
    const int offB0 = (n_ofs + lrow) * BK + ((quad ^ e_) << 3);                \
    f32x4 acc[(TM) / 32][4] = {};                                              \
    _Pragma("unroll") for (int i = 0; i < (TM) / 32; i++)                      \
        g2l16(gA + (size_t)(32 * i) * D_, ldsA + sdst + i * 32 * BK);          \
    _Pragma("unroll") for (int i = 0; i < 4; i++)                              \
        g2l16(gB + (size_t)(32 * i) * D_, ldsB + sdst + i * 32 * BK);          \
    for (int it = 0; it < D_ / BK; it++) {                                     \
        const int cur = it & 1;                                                \
        const int abase = cur * (TM) * BK, bbase = cur * 128 * BK;             \
        __syncthreads(); /* drains DMA for buf[cur]; compute of cur^1 done */  \
        if (it + 1 < D_ / BK) {                                                \
            const int kt2 = (it + 1) * BK;                                     \
            const int nb = cur ^ 1;                                            \
            _Pragma("unroll") for (int i = 0; i < (TM) / 32; i++)              \
                g2l16(gA + (size_t)(32 * i) * D_ + kt2,                        \
                      ldsA + nb * (TM) * BK + sdst + i * 32 * BK);             \
            _Pragma("unroll") for (int i = 0; i < 4; i++)                      \
                g2l16(gB + (size_t)(32 * i) * D_ + kt2,                        \
                      ldsB + nb * 128 * BK + sdst + i * 32 * BK);              \
        }                                                                      \
        _Pragma("unroll") for (int ks = 0; ks < 2; ks++) {                     \
            const int oa = abase + (offA0 ^ (ks << 5));                       \
            const int ob = bbase + (offB0 ^ (ks << 5));                       \
            bf16x8 af[(TM) / 32], bfr[4];                                      \
            _Pragma("unroll") for (int c = 0; c < (TM) / 32; c++)              \
                af[c] = *(const bf16x8*)&ldsA[oa + c * 16 * BK];               \
            _Pragma("unroll") for (int c = 0; c < 4; c++)                      \
                bfr[c] = *(const bf16x8*)&ldsB[ob + c * 16 * BK];              \
            _Pragma("unroll") for (int i = 0; i < (TM) / 32; i++)              \
                _Pragma("unroll") for (int j = 0; j < 4; j++)                  \
                    acc[i][j] = mfma16(af[i], bfr[j], acc[i][j]);              \
        }                                                                      \
    }

// ---------------- QKV projection GEMM (64x128 tile, grid 2304 = 9/CU) -------
__global__ __launch_bounds__(256) void gemm_qkv(const u16* __restrict__ X,
                                                const u16* __restrict__ W,
                                                const float* __restrict__ bqkv,
                                                u16* __restrict__ Qs,
                                                u16* __restrict__ Ks,
                                                u16* __restrict__ Vt) {
    GEMM_CORE(X, W, 64, 24576)
    __syncthreads();  // all waves done reading ldsA/ldsB; smem becomes C-tile
    u16* ldsC = smem;
#pragma unroll
    for (int cn = 0; cn < 4; cn++) {
        const int E = nbase + n_ofs + cn * 16;  // global out-feature base
        const int h = E / 192;
        const int rr = E - h * 192;
        const int kind = rr >> 6;               // 0=Q 1=K 2=V
        const float bias = bqkv[E + lrow];
        if (kind == 2) {
            const int d = (rr & 63) + lrow;
#pragma unroll
            for (int cm = 0; cm < 2; cm++) {
                const int t0 = mbase + m_ofs + cm * 16 + quad * 4;
                const int b_ = t0 >> 11, n0 = t0 & (N_ - 1);
                const size_t bh = (size_t)(b_ * H_ + h);
                uint2 pk;
                pk.x = (u32)f2bf(acc[cm][cn][0] + bias) |
                       ((u32)f2bf(acc[cm][cn][1] + bias) << 16);
                pk.y = (u32)f2bf(acc[cm][cn][2] + bias) |
                       ((u32)f2bf(acc[cm][cn][3] + bias) << 16);
                *(uint2*)&Vt[(bh * HD_ + d) * N_ + n0] = pk;
            }
        } else {
            const int fcol = n_ofs + cn * 16 + lrow;  // block-local feature
            const float scale = (kind == 0) ? QSCALE : 1.0f;
#pragma unroll
            for (int cm = 0; cm < 2; cm++)
#pragma unroll
                for (int r = 0; r < 4; r++) {
                    const int tok = m_ofs + cm * 16 + quad * 4 + r;
                    ldsC[tok * CPITCH + fcol] =
                        f2bf((acc[cm][cn][r] + bias) * scale);
                }
        }
    }
    __syncthreads();
    // store phase: thread -> (token = tid>>2, sub = half(64f) x j-half)
    {
        const int tok = tid >> 2, sub = tid & 3;
        const int fh = sub >> 1, jh = sub & 1;
        const int gf = nbase + fh * 64;          // global feature base of half
        const int kind2 = (gf >> 6) % 3;
        if (kind2 != 2) {
            const int h2 = gf / 192;
            const int t = mbase + tok;
            const int b2 = t >> 11, n2 = t & (N_ - 1);
            u16* dst = (kind2 == 0 ? Qs : Ks) +
                       ((size_t)(b2 * H_ + h2) * N_ + n2) * HD_;
            const u16* src = &ldsC[tok * CPITCH + fh * 64];
#pragma unroll
            for (int j = 0; j < 4; j++)
                *(uint4*)&dst[(jh * 4 + j) * 8] =
                    *(const uint4*)&src[(jh * 4 + j) * 8];
        }
    }
}

// ---------------- output projection GEMM (64x128 tile, 768 blocks) ----------
__global__ __launch_bounds__(256) void gemm_out(const u16* __restrict__ X2,
                                                const u16* __restrict__ W,
                                                const float* __restrict__ bmsa,
                                                float* __restrict__ out) {
    GEMM_CORE(X2, W, 64, 24576)
#pragma unroll
    for (int cn = 0; cn < 4; cn++) {
        const int col = nbase + n_ofs + cn * 16 + lrow;
        const float bias = bmsa[col];
#pragma unroll
        for (int cm = 0; cm < 2; cm++) {
#pragma unroll
            for (int r = 0; r < 4; r++) {
                const int t = mbase + m_ofs + cm * 16 + quad * 4 + r;
                out[(size_t)t * D_ + col] = acc[cm][cn][r] + bias;
            }
        }
    }
}

// ------ Flash attention R7: barrier-free, K/V direct from L2 (m169) ---------
// R6 result: XCD swizzle made K/V L2-resident (FETCH 104.5->18.5 MB) but dur
// flat -> memory off the critical path; the per-iter barrier chain is the
// bottleneck. Fix: drop K/V LDS staging entirely (m169: "staging L2-fit data
// is pure overhead"). K/V frags read directly from global (L2-hit ~200cy),
// ldsP is per-wave private -> NO __syncthreads in the loop. All 12 waves/CU
// run independently -> max cross-wave latency hiding (m114). LDS 50->17.4 KB.
// V loads issued between QK and softmax so exp2/pack covers their latency.
__global__ __launch_bounds__(256, 3) void flash_attn(const u16* __restrict__ Qs,
                                                     const u16* __restrict__ Ks,
                                                     const u16* __restrict__ Vt,
                                                     u16* __restrict__ X2) {
    __shared__ u16 ldsP[4][2][16][68];  // 17.4 KB: P roundtrip only (per-wave)
    const int tid = threadIdx.x;
    const int wave = tid >> 6, lane = tid & 63;
    const int lrow = lane & 15, quad = lane >> 4;
    // XCD-locality decode (R6, kept: prerequisite for L2-resident K/V)
    const int x_ = blockIdx.x;
    const int j_ = x_ >> 3;
    const int bh = (x_ & 7) * 6 + (j_ >> 4);   // 6 bh per XCD
    const int qb = j_ & 15;
    const int qbase = qb * 128 + wave * 32;
    const int b = bh / H_, h = bh - b * H_;

    const u16* Kb = Ks + (size_t)bh * N_ * HD_;
    const u16* Vb = Vt + (size_t)bh * HD_ * N_;
    // per-lane fragment base pointers (plain quad*8 cols; no LDS, no swizzle)
    const u16* Kl = Kb + (size_t)lrow * HD_ + quad * 8;
    const u16* Vl = Vb + (size_t)lrow * N_ + quad * 8;

    bf16x8 qa[2][2];
#pragma unroll
    for (int t = 0; t < 2; t++) {
        const u16* Qb = Qs + ((size_t)bh * N_ + qbase + t * 16 + lrow) * HD_ + quad * 8;
        qa[t][0] = *(const bf16x8*)(Qb);
        qa[t][1] = *(const bf16x8*)(Qb + 32);
    }

    const short onebf = (short)0x3F80;  // bf16 1.0
    const bf16x8 ones = {onebf, onebf, onebf, onebf, onebf, onebf, onebf, onebf};

    f32x4 Oacc[2][4] = {};
    f32x4 lacc[2] = {};

    for (int it = 0; it < N_ / 64; it++) {
        const int kt = it << 6;
        // ---- K fragments direct from global (A-operand: A[m=key][k=d]) ----
        bf16x8 kf[8];
#pragma unroll
        for (int c = 0; c < 4; c++) {
            const u16* kp = Kl + (size_t)(kt + c * 16) * HD_;
            kf[2 * c]     = *(const bf16x8*)(kp);
            kf[2 * c + 1] = *(const bf16x8*)(kp + 32);
        }
        // ---- S^T = K Q^T : lane holds (key=c*16+quad*4+r, q=lrow) ----
        f32x4 s[2][4] = {};
        __builtin_amdgcn_s_setprio(1);
#pragma unroll
        for (int t = 0; t < 2; t++)
#pragma unroll
            for (int c = 0; c < 4; c++) {
                s[t][c] = mfma16(kf[2 * c], qa[t][0], s[t][c]);
                s[t][c] = mfma16(kf[2 * c + 1], qa[t][1], s[t][c]);
            }
        __builtin_amdgcn_s_setprio(0);
        // ---- V fragments direct from global (B-operand: B[k=key][col=d]);
        //      issued here so exp2/pack/P-roundtrip hides their L2 latency ----
        bf16x8 vf[8];
#pragma unroll
        for (int c = 0; c < 4; c++) {
            const u16* vp = Vl + (size_t)(c * 16) * N_ + kt;
            vf[2 * c]     = *(const bf16x8*)(vp);
            vf[2 * c + 1] = *(const bf16x8*)(vp + 32);
        }
        // ---- P = 2^S (raw v_exp_f32), truncate-pack pairs -> b64 store ----
        // (truncation bias cancels: l sums the same truncated bf16 P)
#pragma unroll
        for (int t = 0; t < 2; t++)
#pragma unroll
            for (int c = 0; c < 4; c++) {
                u32 b0 = __float_as_uint(__builtin_amdgcn_exp2f(s[t][c][0]));
                u32 b1 = __float_as_uint(__builtin_amdgcn_exp2f(s[t][c][1]));
                u32 b2 = __float_as_uint(__builtin_amdgcn_exp2f(s[t][c][2]));
                u32 b3 = __float_as_uint(__builtin_amdgcn_exp2f(s[t][c][3]));
                uint2 pk;
                pk.x = __builtin_amdgcn_perm(b1, b0, 0x07060302u);
                pk.y = __builtin_amdgcn_perm(b3, b2, 0x07060302u);
                *(uint2*)&ldsP[wave][t][lrow][c * 16 + quad * 4] = pk;
            }
        bf16x8 pa[2][2];
#pragma unroll
        for (int t = 0; t < 2; t++) {
            pa[t][0] = *(const bf16x8*)&ldsP[wave][t][lrow][quad * 8];
            pa[t][1] = *(const bf16x8*)&ldsP[wave][t][lrow][32 + quad * 8];
        }
        // ---- row sums via MFMA + O += P V (one prio-1 MFMA cluster) ----
        __builtin_amdgcn_s_setprio(1);
#pragma unroll
        for (int t = 0; t < 2; t++) {
            lacc[t] = mfma16(pa[t][0], ones, lacc[t]);
            lacc[t] = mfma16(pa[t][1], ones, lacc[t]);
        }
#pragma unroll
        for (int c = 0; c < 4; c++) {
#pragma unroll
            for (int t = 0; t < 2; t++) {
                Oacc[t][c] = mfma16(pa[t][0], vf[2 * c], Oacc[t][c]);
                Oacc[t][c] = mfma16(pa[t][1], vf[2 * c + 1], Oacc[t][c]);
            }
        }
        __builtin_amdgcn_s_setprio(0);
    }
    // ---- epilogue: lacc[t][r] is the row sum (row = quad*4+r) ----
#pragma unroll
    for (int t = 0; t < 2; t++)
#pragma unroll
        for (int r = 0; r < 4; r++) {
            const float inv = 1.0f / lacc[t][r];
            const int qrow = qbase + t * 16 + quad * 4 + r;
#pragma unroll
            for (int c = 0; c < 4; c++) {
                X2[((size_t)b * N_ + qrow) * D_ + h * HD_ + c * 16 + lrow] =
                    f2bf(Oacc[t][c][r] * inv);
            }
        }
}

extern "C" void kernel_launch(void* const* d_in, const int* in_sizes, int n_in,
                              void* d_out, int out_size, void* d_ws, size_t ws_size,
                              hipStream_t stream) {
    const float* z    = (const float*)d_in[0];
    const float* Wqkv = (const float*)d_in[1];
    const float* bqkv = (const float*)d_in[2];
    const float* Wmsa = (const float*)d_in[3];
    const float* bmsa = (const float*)d_in[4];
    float* out = (float*)d_out;

    u16* Xbf = (u16*)d_ws;
    u16* Wqb = Xbf + (size_t)NTOK * D_;
    u16* Wmb = Wqb + (size_t)NE * D_;
    u16* Qs  = Wmb + (size_t)D_ * D_;
    u16* Ks  = Qs + (size_t)B_ * H_ * N_ * HD_;
    u16* Vt  = Ks + (size_t)B_ * H_ * N_ * HD_;
    u16* X2  = Vt + (size_t)B_ * H_ * N_ * HD_;

    const int ntot = NZ4 + NWQ4 + NWM4;
    cvt_all<<<(ntot + 255) / 256, 256, 0, stream>>>(z, Wqkv, Wmsa, Xbf, Wqb, Wmb);

    // 1D grids; GEMM_CORE / flash decode XCD-locality mapping from blockIdx.x.
    gemm_qkv<<<dim3((NTOK / 64) * (NE / 128)), 256, 0, stream>>>(Xbf, Wqb, bqkv, Qs, Ks, Vt);
    flash_attn<<<dim3(768), 256, 0, stream>>>(Qs, Ks, Vt, X2);
    gemm_out<<<dim3((NTOK / 64) * (D_ / 128)), 256, 0, stream>>>(X2, Wmb, bmsa, out);
}

// Round 9
// 215.599 us; speedup vs baseline: 1.4470x; 1.4470x over previous
//
#include <hip/hip_runtime.h>

typedef unsigned short u16;
typedef unsigned int u32;
typedef __attribute__((ext_vector_type(8))) short bf16x8;
typedef __attribute__((ext_vector_type(4))) float f32x4;

#define B_ 4
#define H_ 12
#define N_ 2048
#define D_ 768
#define HD_ 64
#define NTOK (B_ * N_)      /* 8192 */
#define NE   (H_ * 3 * HD_) /* 2304 */

#define BK 64
#define CPITCH 144  /* qkv epilogue LDS C-tile pitch (16B-aligned rows) */

// 1/sqrt(64) * log2(e): Q pre-scale so attention uses exp2 (bare v_exp_f32)
#define QSCALE 0.18033688011112042f

__device__ __forceinline__ u16 f2bf(float f) {
    u32 u = __float_as_uint(f);
    u += 0x7fffu + ((u >> 16) & 1u);
    return (u16)(u >> 16);
}

__device__ __forceinline__ f32x4 mfma16(bf16x8 a, bf16x8 b, f32x4 c) {
    return __builtin_amdgcn_mfma_f32_16x16x32_bf16(a, b, c, 0, 0, 0);
}

// async global->LDS, 16B per lane. LDS dest = wave-uniform base + lane*16.
__device__ __forceinline__ void g2l16(const u16* g, u16* l) {
    __builtin_amdgcn_global_load_lds(
        (const __attribute__((address_space(1))) void*)g,
        (__attribute__((address_space(3))) void*)l, 16, 0, 0);
}

// ---------------- f32 -> bf16 conversion, WEIGHTS ONLY (R8) -----------------
// z conversion is fused into gemm_qkv's A-staging (saves ~38 MB of traffic).
#define NWQ4 (NE * D_ / 4)
#define NWM4 (D_ * D_ / 4)
__global__ __launch_bounds__(256) void cvt_w(const float* __restrict__ Wq,
                                             const float* __restrict__ Wm,
                                             u16* __restrict__ Wqb,
                                             u16* __restrict__ Wmb) {
    int i = blockIdx.x * blockDim.x + threadIdx.x;
    const float* src;
    u16* dst;
    int j;
    if (i < NWQ4) {
        src = Wq; dst = Wqb; j = i;
    } else if (i < NWQ4 + NWM4) {
        src = Wm; dst = Wmb; j = i - NWQ4;
    } else {
        return;
    }
    float4 v = ((const float4*)src)[j];
    u32 lo = (u32)f2bf(v.x) | ((u32)f2bf(v.y) << 16);
    u32 hi = (u32)f2bf(v.z) | ((u32)f2bf(v.w) << 16);
    ((uint2*)dst)[j] = make_uint2(lo, hi);
}

// ============ GEMM core v3 (R3 exact): single-barrier dbuf + XCD supertile ==
// R4: 3-deep BK=32 counted-vmcnt pipeline REGRESSED (+23us). R5: setprio in
// the MFMA cluster ~null. R7: direct-from-L2 fragment loads REGRESSED 2.7x
// (scattered 16-segment VMEM; staging via global_load_lds is structurally
// required). Residency (3 blk/CU) + simple loop + XCD A-slice locality wins.
#define GEMM_CORE(Xp, Wp, TM, SMELEMS)                                         \
    __shared__ u16 smem[SMELEMS];                                              \
    u16* ldsA = smem;                 /* [2][TM*BK] */                         \
    u16* ldsB = smem + 2 * (TM) * BK; /* [2][128*BK] */                        \
    const int tid = threadIdx.x;                                               \
    const int wave = tid >> 6, lane = tid & 63;                                \
    const int lrow = lane & 15, quad = lane >> 4;                              \
    const int flat_ = blockIdx.x;                                              \
    const int mbase = (((flat_ & 7) << 4) | ((flat_ >> 3) & 15)) * (TM);       \
    const int nbase = (flat_ >> 7) * 128;                                      \
    const int srow = tid >> 3;      /* 0..31 */                                \
    const int schunk = tid & 7;                                                \
    const int sk = (schunk ^ (srow & 7)) << 3; /* swizzled global k-offset */  \
    const int sdst = srow * BK + schunk * 8;   /* lane-contiguous LDS dest */  \
    const u16* gA = Xp + (size_t)(mbase + srow) * D_ + sk;                     \
    const u16* gB = Wp + (size_t)(nbase + srow) * D_ + sk;                     \
    const int m_ofs = (wave >> 1) * ((TM) / 2);                                \
    const int n_ofs = (wave & 1) * 64;                                         \
    const int e_ = lrow & 7;                                                   \
    const int offA0 = (m_ofs + lrow) * BK + ((quad ^ e_) << 3);                \
    const int offB0 = (n_ofs + lrow) * BK + ((quad ^ e_) << 3);                \
    f32x4 acc[(TM) / 32][4] = {};                                              \
    _Pragma("unroll") for (int i = 0; i < (TM) / 32; i++)                      \
        g2l16(gA + (size_t)(32 * i) * D_, ldsA + sdst + i * 32 * BK);          \
    _Pragma("unroll") for (int i = 0; i < 4; i++)                              \
        g2l16(gB + (size_t)(32 * i) * D_, ldsB + sdst + i * 32 * BK);          \
    for (int it = 0; it < D_ / BK; it++) {                                     \
        const int cur = it & 1;                                                \
        const int abase = cur * (TM) * BK, bbase = cur * 128 * BK;             \
        __syncthreads(); /* drains DMA for buf[cur]; compute of cur^1 done */  \
        if (it + 1 < D_ / BK) {                                                \
            const int kt2 = (it + 1) * BK;                                     \
            const int nb = cur ^ 1;                                            \
            _Pragma("unroll") for (int i = 0; i < (TM) / 32; i++)              \
                g2l16(gA + (size_t)(32 * i) * D_ + kt2,                        \
                      ldsA + nb * (TM) * BK + sdst + i * 32 * BK);             \
            _Pragma("unroll") for (int i = 0; i < 4; i++)                      \
                g2l16(gB + (size_t)(32 * i) * D_ + kt2,                        \
                      ldsB + nb * 128 * BK + sdst + i * 32 * BK);              \
        }                                                                      \
        _Pragma("unroll") for (int ks = 0; ks < 2; ks++) {                     \
            const int oa = abase + (offA0 ^ (ks << 5));                       \
            const int ob = bbase + (offB0 ^ (ks << 5));                       \
            bf16x8 af[(TM) / 32], bfr[4];                                      \
            _Pragma("unroll") for (int c = 0; c < (TM) / 32; c++)              \
                af[c] = *(const bf16x8*)&ldsA[oa + c * 16 * BK];               \
            _Pragma("unroll") for (int c = 0; c < 4; c++)                      \
                bfr[c] = *(const bf16x8*)&ldsB[ob + c * 16 * BK];               \
            _Pragma("unroll") for (int i = 0; i < (TM) / 32; i++)              \
                _Pragma("unroll") for (int j = 0; j < 4; j++)                  \
                    acc[i][j] = mfma16(af[i], bfr[j], acc[i][j]);              \
        }                                                                      \
    }

// -------- QKV projection GEMM with FUSED z->bf16 A-staging (R8) -------------
// A-path: f32 z loaded to regs right after the barrier (issue-early), MFMAs
// run, then cvt+ds_write into buf[cur^1] (write-late, T14) — HBM latency
// hides under the MFMA phase. B-path unchanged (g2l16 DMA of bf16 weights).
// Numerics identical to the old cvt->g2l16 path (same f2bf on same f32).
__global__ __launch_bounds__(256) void gemm_qkv(const float* __restrict__ Z,
                                                const u16* __restrict__ W,
                                                const float* __restrict__ bqkv,
                                                u16* __restrict__ Qs,
                                                u16* __restrict__ Ks,
                                                u16* __restrict__ Vt) {
    __shared__ u16 smem[24576];
    u16* ldsA = smem;                 /* [2][64*64] */
    u16* ldsB = smem + 2 * 64 * BK;   /* [2][128*64] */
    const int tid = threadIdx.x;
    const int wave = tid >> 6, lane = tid & 63;
    const int lrow = lane & 15, quad = lane >> 4;
    const int flat_ = blockIdx.x;
    const int mbase = (((flat_ & 7) << 4) | ((flat_ >> 3) & 15)) * 64;
    const int nbase = (flat_ >> 7) * 128;
    const int srow = tid >> 3;      /* 0..31 */
    const int schunk = tid & 7;
    const int sk = (schunk ^ (srow & 7)) << 3;
    const int sdst = srow * BK + schunk * 8;
    const float* gZ = Z + (size_t)(mbase + srow) * D_ + sk;
    const u16* gB = W + (size_t)(nbase + srow) * D_ + sk;
    const int m_ofs = (wave >> 1) * 32;
    const int n_ofs = (wave & 1) * 64;
    const int e_ = lrow & 7;
    const int offA0 = (m_ofs + lrow) * BK + ((quad ^ e_) << 3);
    const int offB0 = (n_ofs + lrow) * BK + ((quad ^ e_) << 3);
    f32x4 acc[2][4] = {};
    // prologue: B(t0) via DMA; A(t0) via load+cvt+write (one-time stall ok)
#pragma unroll
    for (int i = 0; i < 4; i++)
        g2l16(gB + (size_t)(32 * i) * D_, ldsB + sdst + i * 32 * BK);
#pragma unroll
    for (int i = 0; i < 2; i++) {
        float4 f0 = *(const float4*)(gZ + (size_t)(32 * i) * D_);
        float4 f1 = *(const float4*)(gZ + (size_t)(32 * i) * D_ + 4);
        uint4 pk;
        pk.x = (u32)f2bf(f0.x) | ((u32)f2bf(f0.y) << 16);
        pk.y = (u32)f2bf(f0.z) | ((u32)f2bf(f0.w) << 16);
        pk.z = (u32)f2bf(f1.x) | ((u32)f2bf(f1.y) << 16);
        pk.w = (u32)f2bf(f1.z) | ((u32)f2bf(f1.w) << 16);
        *(uint4*)&ldsA[sdst + i * 32 * BK] = pk;
    }
    for (int it = 0; it < D_ / BK; it++) {
        const int cur = it & 1;
        const int abase = cur * 64 * BK, bbase = cur * 128 * BK;
        __syncthreads();  // drains B DMA for buf[cur]; A writes of cur visible
        float4 fA[2][2];
        const bool has_next = (it + 1 < D_ / BK);
        if (has_next) {
            const int kt2 = (it + 1) * BK;
            const int nb = cur ^ 1;
#pragma unroll
            for (int i = 0; i < 4; i++)
                g2l16(gB + (size_t)(32 * i) * D_ + kt2,
                      ldsB + nb * 128 * BK + sdst + i * 32 * BK);
#pragma unroll
            for (int i = 0; i < 2; i++) {   // issue-early: f32 A loads to regs
                fA[i][0] = *(const float4*)(gZ + (size_t)(32 * i) * D_ + kt2);
                fA[i][1] = *(const float4*)(gZ + (size_t)(32 * i) * D_ + kt2 + 4);
            }
        }
#pragma unroll
        for (int ks = 0; ks < 2; ks++) {
            const int oa = abase + (offA0 ^ (ks << 5));
            const int ob = bbase + (offB0 ^ (ks << 5));
            bf16x8 af[2], bfr[4];
#pragma unroll
            for (int c = 0; c < 2; c++)
                af[c] = *(const bf16x8*)&ldsA[oa + c * 16 * BK];
#pragma unroll
            for (int c = 0; c < 4; c++)
                bfr[c] = *(const bf16x8*)&ldsB[ob + c * 16 * BK];
#pragma unroll
            for (int i = 0; i < 2; i++)
#pragma unroll
                for (int j = 0; j < 4; j++)
                    acc[i][j] = mfma16(af[i], bfr[j], acc[i][j]);
        }
        if (has_next) {                 // write-late: cvt + ds_write A(t+1)
            const int nb = cur ^ 1;
#pragma unroll
            for (int i = 0; i < 2; i++) {
                uint4 pk;
                pk.x = (u32)f2bf(fA[i][0].x) | ((u32)f2bf(fA[i][0].y) << 16);
                pk.y = (u32)f2bf(fA[i][0].z) | ((u32)f2bf(fA[i][0].w) << 16);
                pk.z = (u32)f2bf(fA[i][1].x) | ((u32)f2bf(fA[i][1].y) << 16);
                pk.w = (u32)f2bf(fA[i][1].z) | ((u32)f2bf(fA[i][1].w) << 16);
                *(uint4*)&ldsA[nb * 64 * BK + sdst + i * 32 * BK] = pk;
            }
        }
    }
    __syncthreads();  // all waves done reading ldsA/ldsB; smem becomes C-tile
    u16* ldsC = smem;
#pragma unroll
    for (int cn = 0; cn < 4; cn++) {
        const int E = nbase + n_ofs + cn * 16;  // global out-feature base
        const int h = E / 192;
        const int rr = E - h * 192;
        const int kind = rr >> 6;               // 0=Q 1=K 2=V
        const float bias = bqkv[E + lrow];
        if (kind == 2) {
            const int d = (rr & 63) + lrow;
#pragma unroll
            for (int cm = 0; cm < 2; cm++) {
                const int t0 = mbase + m_ofs + cm * 16 + quad * 4;
                const int b_ = t0 >> 11, n0 = t0 & (N_ - 1);
                const size_t bh = (size_t)(b_ * H_ + h);
                uint2 pk;
                pk.x = (u32)f2bf(acc[cm][cn][0] + bias) |
                       ((u32)f2bf(acc[cm][cn][1] + bias) << 16);
                pk.y = (u32)f2bf(acc[cm][cn][2] + bias) |
                       ((u32)f2bf(acc[cm][cn][3] + bias) << 16);
                *(uint2*)&Vt[(bh * HD_ + d) * N_ + n0] = pk;
            }
        } else {
            const int fcol = n_ofs + cn * 16 + lrow;  // block-local feature
            const float scale = (kind == 0) ? QSCALE : 1.0f;
#pragma unroll
            for (int cm = 0; cm < 2; cm++)
#pragma unroll
                for (int r = 0; r < 4; r++) {
                    const int tok = m_ofs + cm * 16 + quad * 4 + r;
                    ldsC[tok * CPITCH + fcol] =
                        f2bf((acc[cm][cn][r] + bias) * scale);
                }
        }
    }
    __syncthreads();
    // store phase: thread -> (token = tid>>2, sub = half(64f) x j-half)
    {
        const int tok = tid >> 2, sub = tid & 3;
        const int fh = sub >> 1, jh = sub & 1;
        const int gf = nbase + fh * 64;          // global feature base of half
        const int kind2 = (gf >> 6) % 3;
        if (kind2 != 2) {
            const int h2 = gf / 192;
            const int t = mbase + tok;
            const int b2 = t >> 11, n2 = t & (N_ - 1);
            u16* dst = (kind2 == 0 ? Qs : Ks) +
                       ((size_t)(b2 * H_ + h2) * N_ + n2) * HD_;
            const u16* src = &ldsC[tok * CPITCH + fh * 64];
#pragma unroll
            for (int j = 0; j < 4; j++)
                *(uint4*)&dst[(jh * 4 + j) * 8] =
                    *(const uint4*)&src[(jh * 4 + j) * 8];
        }
    }
}

// ---------------- output projection GEMM (64x128 tile, 768 blocks) ----------
__global__ __launch_bounds__(256) void gemm_out(const u16* __restrict__ X2,
                                                const u16* __restrict__ W,
                                                const float* __restrict__ bmsa,
                                                float* __restrict__ out) {
    GEMM_CORE(X2, W, 64, 24576)
#pragma unroll
    for (int cn = 0; cn < 4; cn++) {
        const int col = nbase + n_ofs + cn * 16 + lrow;
        const float bias = bmsa[col];
#pragma unroll
        for (int cm = 0; cm < 2; cm++) {
#pragma unroll
            for (int r = 0; r < 4; r++) {
                const int t = mbase + m_ofs + cm * 16 + quad * 4 + r;
                out[(size_t)t * D_ + col] = acc[cm][cn][r] + bias;
            }
        }
    }
}

// ---------------- Flash attention (R3 exact: 4-wave + T5 setprio) -----------
// R9: latency-bound (2-wave variant regressed). R6: XCD swizzle cut FETCH
// 5.7x but dur flat->slightly worse; dropped. R7: direct-from-L2 frag loads
// catastrophic (scattered VMEM). This is the best-measured config: 66.0 us.
__global__ __launch_bounds__(256, 3) void flash_attn(const u16* __restrict__ Qs,
                                                     const u16* __restrict__ Ks,
                                                     const u16* __restrict__ Vt,
                                                     u16* __restrict__ X2) {
    __shared__ u16 ldsK[2][64 * HD_];   // 2 x 8 KB
    __shared__ u16 ldsV[2][64 * HD_];   // 2 x 8 KB
    __shared__ u16 ldsP[4][2][16][68];  // row = q (0..15), col = key (0..63)+pad
    const int tid = threadIdx.x;
    const int wave = tid >> 6, lane = tid & 63;
    const int lrow = lane & 15, quad = lane >> 4;
    const int qbase = blockIdx.x * 128 + wave * 32;
    const int bh = blockIdx.y;
    const int b = bh / H_, h = bh - b * H_;

    const u16* Kb = Ks + (size_t)bh * N_ * HD_;
    const u16* Vb = Vt + (size_t)bh * HD_ * N_;

    const int srow = tid >> 3;
    const int schunk = tid & 7;
    const int skk = (schunk ^ (srow & 7)) << 3;
    const int sdst = srow * HD_ + schunk * 8;

    bf16x8 qa[2][2];
#pragma unroll
    for (int t = 0; t < 2; t++) {
        const u16* Qb = Qs + ((size_t)bh * N_ + qbase + t * 16 + lrow) * HD_ + quad * 8;
        qa[t][0] = *(const bf16x8*)(Qb);
        qa[t][1] = *(const bf16x8*)(Qb + 32);
    }

    const int fofs = (quad ^ (lrow & 7)) << 3;
    const short onebf = (short)0x3F80;  // bf16 1.0
    const bf16x8 ones = {onebf, onebf, onebf, onebf, onebf, onebf, onebf, onebf};

    f32x4 Oacc[2][4] = {};
    f32x4 lacc[2] = {};

    {   // prologue: stage tile 0 into buffer 0
        const u16* gK = Kb + (size_t)srow * HD_ + skk;
        g2l16(gK, &ldsK[0][sdst]);
        g2l16(gK + (size_t)32 * HD_, &ldsK[0][sdst + 32 * HD_]);
        const u16* gV = Vb + (size_t)srow * N_ + skk;
        g2l16(gV, &ldsV[0][sdst]);
        g2l16(gV + (size_t)32 * N_, &ldsV[0][sdst + 32 * HD_]);
    }

    for (int it = 0; it < N_ / 64; it++) {
        const int cur = it & 1;
        __syncthreads();  // drains DMA for buf[cur]; waves done with buf[cur^1]
        if (it + 1 < N_ / 64) {
            const int kt2 = (it + 1) << 6;
            const u16* gK = Kb + (size_t)(kt2 + srow) * HD_ + skk;
            g2l16(gK, &ldsK[cur ^ 1][sdst]);
            g2l16(gK + (size_t)32 * HD_, &ldsK[cur ^ 1][sdst + 32 * HD_]);
            const u16* gV = Vb + (size_t)srow * N_ + kt2 + skk;
            g2l16(gV, &ldsV[cur ^ 1][sdst]);
            g2l16(gV + (size_t)32 * N_, &ldsV[cur ^ 1][sdst + 32 * HD_]);
        }
        // ---- K fragments from LDS (A-operand: A[m=key][k=d]) ----
        bf16x8 kf[8];
#pragma unroll
        for (int c = 0; c < 4; c++) {
            const int o = (c * 16 + lrow) * HD_ + fofs;
            kf[2 * c]     = *(const bf16x8*)&ldsK[cur][o];
            kf[2 * c + 1] = *(const bf16x8*)&ldsK[cur][o ^ 32];
        }
        // ---- S^T = K Q^T : lane holds (key=c*16+quad*4+r, q=lrow) ----
        f32x4 s[2][4] = {};
        __builtin_amdgcn_s_setprio(1);
#pragma unroll
        for (int t = 0; t < 2; t++)
#pragma unroll
            for (int c = 0; c < 4; c++) {
                s[t][c] = mfma16(kf[2 * c], qa[t][0], s[t][c]);
                s[t][c] = mfma16(kf[2 * c + 1], qa[t][1], s[t][c]);
            }
        __builtin_amdgcn_s_setprio(0);
        // ---- P = 2^S (raw v_exp_f32), truncate-pack pairs -> b64 store ----
        // (truncation bias cancels: l sums the same truncated bf16 P)
#pragma unroll
        for (int t = 0; t < 2; t++)
#pragma unroll
            for (int c = 0; c < 4; c++) {
                u32 b0 = __float_as_uint(__builtin_amdgcn_exp2f(s[t][c][0]));
                u32 b1 = __float_as_uint(__builtin_amdgcn_exp2f(s[t][c][1]));
                u32 b2 = __float_as_uint(__builtin_amdgcn_exp2f(s[t][c][2]));
                u32 b3 = __float_as_uint(__builtin_amdgcn_exp2f(s[t][c][3]));
                uint2 pk;
                pk.x = __builtin_amdgcn_perm(b1, b0, 0x07060302u);
                pk.y = __builtin_amdgcn_perm(b3, b2, 0x07060302u);
                *(uint2*)&ldsP[wave][t][lrow][c * 16 + quad * 4] = pk;
            }
        bf16x8 pa[2][2];
#pragma unroll
        for (int t = 0; t < 2; t++) {
            pa[t][0] = *(const bf16x8*)&ldsP[wave][t][lrow][quad * 8];
            pa[t][1] = *(const bf16x8*)&ldsP[wave][t][lrow][32 + quad * 8];
        }
        // ---- row sums via MFMA + O += P V (one prio-1 MFMA cluster) ----
        __builtin_amdgcn_s_setprio(1);
#pragma unroll
        for (int t = 0; t < 2; t++) {
            lacc[t] = mfma16(pa[t][0], ones, lacc[t]);
            lacc[t] = mfma16(pa[t][1], ones, lacc[t]);
        }
#pragma unroll
        for (int c = 0; c < 4; c++) {
            const int o = (c * 16 + lrow) * HD_ + fofs;
            bf16x8 v0 = *(const bf16x8*)&ldsV[cur][o];
            bf16x8 v1 = *(const bf16x8*)&ldsV[cur][o ^ 32];
#pragma unroll
            for (int t = 0; t < 2; t++) {
                Oacc[t][c] = mfma16(pa[t][0], v0, Oacc[t][c]);
                Oacc[t][c] = mfma16(pa[t][1], v1, Oacc[t][c]);
            }
        }
        __builtin_amdgcn_s_setprio(0);
    }
    // ---- epilogue: lacc[t][r] is the row sum (row = quad*4+r) ----
#pragma unroll
    for (int t = 0; t < 2; t++)
#pragma unroll
        for (int r = 0; r < 4; r++) {
            const float inv = 1.0f / lacc[t][r];
            const int qrow = qbase + t * 16 + quad * 4 + r;
#pragma unroll
            for (int c = 0; c < 4; c++) {
                X2[((size_t)b * N_ + qrow) * D_ + h * HD_ + c * 16 + lrow] =
                    f2bf(Oacc[t][c][r] * inv);
            }
        }
}

extern "C" void kernel_launch(void* const* d_in, const int* in_sizes, int n_in,
                              void* d_out, int out_size, void* d_ws, size_t ws_size,
                              hipStream_t stream) {
    const float* z    = (const float*)d_in[0];
    const float* Wqkv = (const float*)d_in[1];
    const float* bqkv = (const float*)d_in[2];
    const float* Wmsa = (const float*)d_in[3];
    const float* bmsa = (const float*)d_in[4];
    float* out = (float*)d_out;

    u16* Xbf = (u16*)d_ws;                       // unused in R8 (kept layout)
    u16* Wqb = Xbf + (size_t)NTOK * D_;
    u16* Wmb = Wqb + (size_t)NE * D_;
    u16* Qs  = Wmb + (size_t)D_ * D_;
    u16* Ks  = Qs + (size_t)B_ * H_ * N_ * HD_;
    u16* Vt  = Ks + (size_t)B_ * H_ * N_ * HD_;
    u16* X2  = Vt + (size_t)B_ * H_ * N_ * HD_;

    const int ntot = NWQ4 + NWM4;
    cvt_w<<<(ntot + 255) / 256, 256, 0, stream>>>(Wqkv, Wmsa, Wqb, Wmb);

    // 1D grids; GEMM cores decode XCD-supertile (x,y) from blockIdx.x.
    gemm_qkv<<<dim3((NTOK / 64) * (NE / 128)), 256, 0, stream>>>(z, Wqb, bqkv, Qs, Ks, Vt);
    flash_attn<<<dim3(N_ / 128, B_ * H_), 256, 0, stream>>>(Qs, Ks, Vt, X2);
    gemm_out<<<dim3((NTOK / 64) * (D_ / 128)), 256, 0, stream>>>(X2, Wmb, bmsa, out);
}

// Round 10
// 210.404 us; speedup vs baseline: 1.4827x; 1.0247x over previous
//
#include <hip/hip_runtime.h>

typedef unsigned short u16;
typedef unsigned int u32;
typedef __attribute__((ext_vector_type(8))) short bf16x8;
typedef __attribute__((ext_vector_type(4))) float f32x4;

#define B_ 4
#define H_ 12
#define N_ 2048
#define D_ 768
#define HD_ 64
#define NTOK (B_ * N_)      /* 8192 */
#define NE   (H_ * 3 * HD_) /* 2304 */

#define BK 64
#define CPITCH 144  /* qkv epilogue LDS C-tile pitch (16B-aligned rows) */

// 1/sqrt(64) * log2(e): Q pre-scale so attention uses exp2 (bare v_exp_f32)
#define QSCALE 0.18033688011112042f

__device__ __forceinline__ u16 f2bf(float f) {
    u32 u = __float_as_uint(f);
    u += 0x7fffu + ((u >> 16) & 1u);
    return (u16)(u >> 16);
}

__device__ __forceinline__ f32x4 mfma16(bf16x8 a, bf16x8 b, f32x4 c) {
    return __builtin_amdgcn_mfma_f32_16x16x32_bf16(a, b, c, 0, 0, 0);
}

// async global->LDS, 16B per lane. LDS dest = wave-uniform base + lane*16.
__device__ __forceinline__ void g2l16(const u16* g, u16* l) {
    __builtin_amdgcn_global_load_lds(
        (const __attribute__((address_space(1))) void*)g,
        (__attribute__((address_space(3))) void*)l, 16, 0, 0);
}

// ---------------- fused f32 -> bf16 conversion (z, Wqkv, Wmsa) ----------------
// R9 lesson: fusing the z-conversion into qkv's A-staging REGRESSED (+18us
// total: f2bf VALU + 8-way-conflicted ds_writes in the barrier-critical
// path, SQ_LDS_BANK_CONFLICT 0->540K). Standalone cvt + g2l16 DMA staging is
// the verified optimum.
#define NZ4  (NTOK * D_ / 4)
#define NWQ4 (NE * D_ / 4)
#define NWM4 (D_ * D_ / 4)
__global__ __launch_bounds__(256) void cvt_all(const float* __restrict__ z,
                                               const float* __restrict__ Wq,
                                               const float* __restrict__ Wm,
                                               u16* __restrict__ Xbf,
                                               u16* __restrict__ Wqb,
                                               u16* __restrict__ Wmb) {
    int i = blockIdx.x * blockDim.x + threadIdx.x;
    const float* src;
    u16* dst;
    int j;
    if (i < NZ4) {
        src = z; dst = Xbf; j = i;
    } else if (i < NZ4 + NWQ4) {
        src = Wq; dst = Wqb; j = i - NZ4;
    } else if (i < NZ4 + NWQ4 + NWM4) {
        src = Wm; dst = Wmb; j = i - NZ4 - NWQ4;
    } else {
        return;
    }
    float4 v = ((const float4*)src)[j];
    u32 lo = (u32)f2bf(v.x) | ((u32)f2bf(v.y) << 16);
    u32 hi = (u32)f2bf(v.z) | ((u32)f2bf(v.w) << 16);
    ((uint2*)dst)[j] = make_uint2(lo, hi);
}

// ============ GEMM core v3 (R3 exact): single-barrier dbuf + XCD supertile ==
// Session ledger for this core: 128^2 tile @2 blk/CU (R10) -23us; 3-deep
// BK=32 counted-vmcnt (R4) -23us; MFMA setprio (R5) ~null; direct-from-L2
// fragment loads (R7, flash) -119us; fused z-cvt staging (R9) -18us.
// Residency (3 blk/CU) + simple single-barrier loop + XCD A-slice locality
// is the verified local optimum for this latency-bound regime.
#define GEMM_CORE(Xp, Wp, TM, SMELEMS)                                         \
    __shared__ u16 smem[SMELEMS];                                              \
    u16* ldsA = smem;                 /* [2][TM*BK] */                         \
    u16* ldsB = smem + 2 * (TM) * BK; /* [2][128*BK] */                        \
    const int tid = threadIdx.x;                                               \
    const int wave = tid >> 6, lane = tid & 63;                                \
    const int lrow = lane & 15, quad = lane >> 4;                              \
    const int flat_ = blockIdx.x;                                              \
    const int mbase = (((flat_ & 7) << 4) | ((flat_ >> 3) & 15)) * (TM);       \
    const int nbase = (flat_ >> 7) * 128;                                      \
    const int srow = tid >> 3;      /* 0..31 */                                \
    const int schunk = tid & 7;                                                \
    const int sk = (schunk ^ (srow & 7)) << 3; /* swizzled global k-offset */  \
    const int sdst = srow * BK + schunk * 8;   /* lane-contiguous LDS dest */  \
    const u16* gA = Xp + (size_t)(mbase + srow) * D_ + sk;                     \
    const u16* gB = Wp + (size_t)(nbase + srow) * D_ + sk;                     \
    const int m_ofs = (wave >> 1) * ((TM) / 2);                                \
    const int n_ofs = (wave & 1) * 64;                                         \
    const int e_ = lrow & 7;                                                   \
    const int offA0 = (m_ofs + lrow) * BK + ((quad ^ e_) << 3);                \
    const int offB0 = (n_ofs + lrow) * BK + ((quad ^ e_) << 3);                \
    f32x4 acc[(TM) / 32][4] = {};                                              \
    _Pragma("unroll") for (int i = 0; i < (TM) / 32; i++)                      \
        g2l16(gA + (size_t)(32 * i) * D_, ldsA + sdst + i * 32 * BK);          \
    _Pragma("unroll") for (int i = 0; i < 4; i++)                              \
        g2l16(gB + (size_t)(32 * i) * D_, ldsB + sdst + i * 32 * BK);          \
    for (int it = 0; it < D_ / BK; it++) {                                     \
        const int cur = it & 1;                                                \
        const int abase = cur * (TM) * BK, bbase = cur * 128 * BK;             \
        __syncthreads(); /* drains DMA for buf[cur]; compute of cur^1 done */  \
        if (it + 1 < D_ / BK) {                                                \
            const int kt2 = (it + 1) * BK;                                     \
            const int nb = cur ^ 1;                                            \
            _Pragma("unroll") for (int i = 0; i < (TM) / 32; i++)              \
                g2l16(gA + (size_t)(32 * i) * D_ + kt2,                        \
                      ldsA + nb * (TM) * BK + sdst + i * 32 * BK);             \
            _Pragma("unroll") for (int i = 0; i < 4; i++)                      \
                g2l16(gB + (size_t)(32 * i) * D_ + kt2,                        \
                      ldsB + nb * 128 * BK + sdst + i * 32 * BK);              \
        }                                                                      \
        _Pragma("unroll") for (int ks = 0; ks < 2; ks++) {                     \
            const int oa = abase + (offA0 ^ (ks << 5));                       \
            const int ob = bbase + (offB0 ^ (ks << 5));                       \
            bf16x8 af[(TM) / 32], bfr[4];                                      \
            _Pragma("unroll") for (int c = 0; c < (TM) / 32; c++)              \
                af[c] = *(const bf16x8*)&ldsA[oa + c * 16 * BK];               \
            _Pragma("unroll") for (int c = 0; c < 4; c++)                      \
                bfr[c] = *(const bf16x8*)&ldsB[ob + c * 16 * BK];              \
            _Pragma("unroll") for (int i = 0; i < (TM) / 32; i++)              \
                _Pragma("unroll") for (int j = 0; j < 4; j++)                  \
                    acc[i][j] = mfma16(af[i], bfr[j], acc[i][j]);              \
        }                                                                      \
    }

// ---------------- QKV projection GEMM (64x128 tile, grid 2304 = 9/CU) -------
__global__ __launch_bounds__(256) void gemm_qkv(const u16* __restrict__ X,
                                                const u16* __restrict__ W,
                                                const float* __restrict__ bqkv,
                                                u16* __restrict__ Qs,
                                                u16* __restrict__ Ks,
                                                u16* __restrict__ Vt) {
    GEMM_CORE(X, W, 64, 24576)
    __syncthreads();  // all waves done reading ldsA/ldsB; smem becomes C-tile
    u16* ldsC = smem;
#pragma unroll
    for (int cn = 0; cn < 4; cn++) {
        const int E = nbase + n_ofs + cn * 16;  // global out-feature base
        const int h = E / 192;
        const int rr = E - h * 192;
        const int kind = rr >> 6;               // 0=Q 1=K 2=V
        const float bias = bqkv[E + lrow];
        if (kind == 2) {
            const int d = (rr & 63) + lrow;
#pragma unroll
            for (int cm = 0; cm < 2; cm++) {
                const int t0 = mbase + m_ofs + cm * 16 + quad * 4;
                const int b_ = t0 >> 11, n0 = t0 & (N_ - 1);
                const size_t bh = (size_t)(b_ * H_ + h);
                uint2 pk;
                pk.x = (u32)f2bf(acc[cm][cn][0] + bias) |
                       ((u32)f2bf(acc[cm][cn][1] + bias) << 16);
                pk.y = (u32)f2bf(acc[cm][cn][2] + bias) |
                       ((u32)f2bf(acc[cm][cn][3] + bias) << 16);
                *(uint2*)&Vt[(bh * HD_ + d) * N_ + n0] = pk;
            }
        } else {
            const int fcol = n_ofs + cn * 16 + lrow;  // block-local feature
            const float scale = (kind == 0) ? QSCALE : 1.0f;
#pragma unroll
            for (int cm = 0; cm < 2; cm++)
#pragma unroll
                for (int r = 0; r < 4; r++) {
                    const int tok = m_ofs + cm * 16 + quad * 4 + r;
                    ldsC[tok * CPITCH + fcol] =
                        f2bf((acc[cm][cn][r] + bias) * scale);
                }
        }
    }
    __syncthreads();
    // store phase: thread -> (token = tid>>2, sub = half(64f) x j-half)
    {
        const int tok = tid >> 2, sub = tid & 3;
        const int fh = sub >> 1, jh = sub & 1;
        const int gf = nbase + fh * 64;          // global feature base of half
        const int kind2 = (gf >> 6) % 3;
        if (kind2 != 2) {
            const int h2 = gf / 192;
            const int t = mbase + tok;
            const int b2 = t >> 11, n2 = t & (N_ - 1);
            u16* dst = (kind2 == 0 ? Qs : Ks) +
                       ((size_t)(b2 * H_ + h2) * N_ + n2) * HD_;
            const u16* src = &ldsC[tok * CPITCH + fh * 64];
#pragma unroll
            for (int j = 0; j < 4; j++)
                *(uint4*)&dst[(jh * 4 + j) * 8] =
                    *(const uint4*)&src[(jh * 4 + j) * 8];
        }
    }
}

// ---------------- output projection GEMM (64x128 tile, 768 blocks) ----------
__global__ __launch_bounds__(256) void gemm_out(const u16* __restrict__ X2,
                                                const u16* __restrict__ W,
                                                const float* __restrict__ bmsa,
                                                float* __restrict__ out) {
    GEMM_CORE(X2, W, 64, 24576)
#pragma unroll
    for (int cn = 0; cn < 4; cn++) {
        const int col = nbase + n_ofs + cn * 16 + lrow;
        const float bias = bmsa[col];
#pragma unroll
        for (int cm = 0; cm < 2; cm++) {
#pragma unroll
            for (int r = 0; r < 4; r++) {
                const int t = mbase + m_ofs + cm * 16 + quad * 4 + r;
                out[(size_t)t * D_ + col] = acc[cm][cn][r] + bias;
            }
        }
    }
}

// ---------------- Flash attention (R3 exact: 4-wave + T5 setprio) -----------
// Ledger: 2-wave/64q (R9) -11us (latency-bound, residency is binding);
// XCD swizzle (R6) FETCH -5.7x but dur flat (memory off critical path);
// barrier-free direct-L2 frags (R7) -119us (scattered VMEM catastrophic).
// 4-wave + dbuf staging + setprio on MFMA clusters = 66.0 us, best measured.
__global__ __launch_bounds__(256, 3) void flash_attn(const u16* __restrict__ Qs,
                                                     const u16* __restrict__ Ks,
                                                     const u16* __restrict__ Vt,
                                                     u16* __restrict__ X2) {
    __shared__ u16 ldsK[2][64 * HD_];   // 2 x 8 KB
    __shared__ u16 ldsV[2][64 * HD_];   // 2 x 8 KB
    __shared__ u16 ldsP[4][2][16][68];  // row = q (0..15), col = key (0..63)+pad
    const int tid = threadIdx.x;
    const int wave = tid >> 6, lane = tid & 63;
    const int lrow = lane & 15, quad = lane >> 4;
    const int qbase = blockIdx.x * 128 + wave * 32;
    const int bh = blockIdx.y;
    const int b = bh / H_, h = bh - b * H_;

    const u16* Kb = Ks + (size_t)bh * N_ * HD_;
    const u16* Vb = Vt + (size_t)bh * HD_ * N_;

    const int srow = tid >> 3;
    const int schunk = tid & 7;
    const int skk = (schunk ^ (srow & 7)) << 3;
    const int sdst = srow * HD_ + schunk * 8;

    bf16x8 qa[2][2];
#pragma unroll
    for (int t = 0; t < 2; t++) {
        const u16* Qb = Qs + ((size_t)bh * N_ + qbase + t * 16 + lrow) * HD_ + quad * 8;
        qa[t][0] = *(const bf16x8*)(Qb);
        qa[t][1] = *(const bf16x8*)(Qb + 32);
    }

    const int fofs = (quad ^ (lrow & 7)) << 3;
    const short onebf = (short)0x3F80;  // bf16 1.0
    const bf16x8 ones = {onebf, onebf, onebf, onebf, onebf, onebf, onebf, onebf};

    f32x4 Oacc[2][4] = {};
    f32x4 lacc[2] = {};

    {   // prologue: stage tile 0 into buffer 0
        const u16* gK = Kb + (size_t)srow * HD_ + skk;
        g2l16(gK, &ldsK[0][sdst]);
        g2l16(gK + (size_t)32 * HD_, &ldsK[0][sdst + 32 * HD_]);
        const u16* gV = Vb + (size_t)srow * N_ + skk;
        g2l16(gV, &ldsV[0][sdst]);
        g2l16(gV + (size_t)32 * N_, &ldsV[0][sdst + 32 * HD_]);
    }

    for (int it = 0; it < N_ / 64; it++) {
        const int cur = it & 1;
        __syncthreads();  // drains DMA for buf[cur]; waves done with buf[cur^1]
        if (it + 1 < N_ / 64) {
            const int kt2 = (it + 1) << 6;
            const u16* gK = Kb + (size_t)(kt2 + srow) * HD_ + skk;
            g2l16(gK, &ldsK[cur ^ 1][sdst]);
            g2l16(gK + (size_t)32 * HD_, &ldsK[cur ^ 1][sdst + 32 * HD_]);
            const u16* gV = Vb + (size_t)srow * N_ + kt2 + skk;
            g2l16(gV, &ldsV[cur ^ 1][sdst]);
            g2l16(gV + (size_t)32 * N_, &ldsV[cur ^ 1][sdst + 32 * HD_]);
        }
        // ---- K fragments from LDS (A-operand: A[m=key][k=d]) ----
        bf16x8 kf[8];
#pragma unroll
        for (int c = 0; c < 4; c++) {
            const int o = (c * 16 + lrow) * HD_ + fofs;
            kf[2 * c]     = *(const bf16x8*)&ldsK[cur][o];
            kf[2 * c + 1] = *(const bf16x8*)&ldsK[cur][o ^ 32];
        }
        // ---- S^T = K Q^T : lane holds (key=c*16+quad*4+r, q=lrow) ----
        f32x4 s[2][4] = {};
        __builtin_amdgcn_s_setprio(1);
#pragma unroll
        for (int t = 0; t < 2; t++)
#pragma unroll
            for (int c = 0; c < 4; c++) {
                s[t][c] = mfma16(kf[2 * c], qa[t][0], s[t][c]);
                s[t][c] = mfma16(kf[2 * c + 1], qa[t][1], s[t][c]);
            }
        __builtin_amdgcn_s_setprio(0);
        // ---- P = 2^S (raw v_exp_f32), truncate-pack pairs -> b64 store ----
        // (truncation bias cancels: l sums the same truncated bf16 P)
#pragma unroll
        for (int t = 0; t < 2; t++)
#pragma unroll
            for (int c = 0; c < 4; c++) {
                u32 b0 = __float_as_uint(__builtin_amdgcn_exp2f(s[t][c][0]));
                u32 b1 = __float_as_uint(__builtin_amdgcn_exp2f(s[t][c][1]));
                u32 b2 = __float_as_uint(__builtin_amdgcn_exp2f(s[t][c][2]));
                u32 b3 = __float_as_uint(__builtin_amdgcn_exp2f(s[t][c][3]));
                uint2 pk;
                pk.x = __builtin_amdgcn_perm(b1, b0, 0x07060302u);
                pk.y = __builtin_amdgcn_perm(b3, b2, 0x07060302u);
                *(uint2*)&ldsP[wave][t][lrow][c * 16 + quad * 4] = pk;
            }
        bf16x8 pa[2][2];
#pragma unroll
        for (int t = 0; t < 2; t++) {
            pa[t][0] = *(const bf16x8*)&ldsP[wave][t][lrow][quad * 8];
            pa[t][1] = *(const bf16x8*)&ldsP[wave][t][lrow][32 + quad * 8];
        }
        // ---- row sums via MFMA + O += P V (one prio-1 MFMA cluster) ----
        __builtin_amdgcn_s_setprio(1);
#pragma unroll
        for (int t = 0; t < 2; t++) {
            lacc[t] = mfma16(pa[t][0], ones, lacc[t]);
            lacc[t] = mfma16(pa[t][1], ones, lacc[t]);
        }
#pragma unroll
        for (int c = 0; c < 4; c++) {
            const int o = (c * 16 + lrow) * HD_ + fofs;
            bf16x8 v0 = *(const bf16x8*)&ldsV[cur][o];
            bf16x8 v1 = *(const bf16x8*)&ldsV[cur][o ^ 32];
#pragma unroll
            for (int t = 0; t < 2; t++) {
                Oacc[t][c] = mfma16(pa[t][0], v0, Oacc[t][c]);
                Oacc[t][c] = mfma16(pa[t][1], v1, Oacc[t][c]);
            }
        }
        __builtin_amdgcn_s_setprio(0);
    }
    // ---- epilogue: lacc[t][r] is the row sum (row = quad*4+r) ----
#pragma unroll
    for (int t = 0; t < 2; t++)
#pragma unroll
        for (int r = 0; r < 4; r++) {
            const float inv = 1.0f / lacc[t][r];
            const int qrow = qbase + t * 16 + quad * 4 + r;
#pragma unroll
            for (int c = 0; c < 4; c++) {
                X2[((size_t)b * N_ + qrow) * D_ + h * HD_ + c * 16 + lrow] =
                    f2bf(Oacc[t][c][r] * inv);
            }
        }
}

extern "C" void kernel_launch(void* const* d_in, const int* in_sizes, int n_in,
                              void* d_out, int out_size, void* d_ws, size_t ws_size,
                              hipStream_t stream) {
    const float* z    = (const float*)d_in[0];
    const float* Wqkv = (const float*)d_in[1];
    const float* bqkv = (const float*)d_in[2];
    const float* Wmsa = (const float*)d_in[3];
    const float* bmsa = (const float*)d_in[4];
    float* out = (float*)d_out;

    u16* Xbf = (u16*)d_ws;
    u16* Wqb = Xbf + (size_t)NTOK * D_;
    u16* Wmb = Wqb + (size_t)NE * D_;
    u16* Qs  = Wmb + (size_t)D_ * D_;
    u16* Ks  = Qs + (size_t)B_ * H_ * N_ * HD_;
    u16* Vt  = Ks + (size_t)B_ * H_ * N_ * HD_;
    u16* X2  = Vt + (size_t)B_ * H_ * N_ * HD_;

    const int ntot = NZ4 + NWQ4 + NWM4;
    cvt_all<<<(ntot + 255) / 256, 256, 0, stream>>>(z, Wqkv, Wmsa, Xbf, Wqb, Wmb);

    // 1D grids; GEMM_CORE decodes XCD-supertile (x,y) from blockIdx.x.
    gemm_qkv<<<dim3((NTOK / 64) * (NE / 128)), 256, 0, stream>>>(Xbf, Wqb, bqkv, Qs, Ks, Vt);
    flash_attn<<<dim3(N_ / 128, B_ * H_), 256, 0, stream>>>(Qs, Ks, Vt, X2);
    gemm_out<<<dim3((NTOK / 64) * (D_ / 128)), 256, 0, stream>>>(X2, Wmb, bmsa, out);
}

// Round 11
// 199.254 us; speedup vs baseline: 1.5657x; 1.0560x over previous
//
#include <hip/hip_runtime.h>

typedef unsigned short u16;
typedef unsigned int u32;
typedef __attribute__((ext_vector_type(8))) short bf16x8;
typedef __attribute__((ext_vector_type(4))) float f32x4;

#define B_ 4
#define H_ 12
#define N_ 2048
#define D_ 768
#define HD_ 64
#define NTOK (B_ * N_)      /* 8192 */
#define NE   (H_ * 3 * HD_) /* 2304 */

#define BK 64
#define CPITCH 144  /* qkv epilogue LDS C-tile pitch (16B-aligned rows) */

// 1/sqrt(64) * log2(e): Q pre-scale so attention uses exp2 (bare v_exp_f32)
#define QSCALE 0.18033688011112042f

__device__ __forceinline__ u16 f2bf(float f) {
    u32 u = __float_as_uint(f);
    u += 0x7fffu + ((u >> 16) & 1u);
    return (u16)(u >> 16);
}

__device__ __forceinline__ f32x4 mfma16(bf16x8 a, bf16x8 b, f32x4 c) {
    return __builtin_amdgcn_mfma_f32_16x16x32_bf16(a, b, c, 0, 0, 0);
}

// async global->LDS, 16B per lane. LDS dest = wave-uniform base + lane*16.
__device__ __forceinline__ void g2l16(const u16* g, u16* l) {
    __builtin_amdgcn_global_load_lds(
        (const __attribute__((address_space(1))) void*)g,
        (__attribute__((address_space(3))) void*)l, 16, 0, 0);
}

// ---------------- fused f32 -> bf16 conversion (z, Wqkv, Wmsa) ----------------
// R9 lesson: fusing the z-conversion into qkv's A-staging REGRESSED (+18us:
// f2bf VALU + 8-way-conflicted ds_writes in the barrier-critical path).
// Standalone cvt + g2l16 DMA staging is the verified optimum.
#define NZ4  (NTOK * D_ / 4)
#define NWQ4 (NE * D_ / 4)
#define NWM4 (D_ * D_ / 4)
__global__ __launch_bounds__(256) void cvt_all(const float* __restrict__ z,
                                               const float* __restrict__ Wq,
                                               const float* __restrict__ Wm,
                                               u16* __restrict__ Xbf,
                                               u16* __restrict__ Wqb,
                                               u16* __restrict__ Wmb) {
    int i = blockIdx.x * blockDim.x + threadIdx.x;
    const float* src;
    u16* dst;
    int j;
    if (i < NZ4) {
        src = z; dst = Xbf; j = i;
    } else if (i < NZ4 + NWQ4) {
        src = Wq; dst = Wqb; j = i - NZ4;
    } else if (i < NZ4 + NWQ4 + NWM4) {
        src = Wm; dst = Wmb; j = i - NZ4 - NWQ4;
    } else {
        return;
    }
    float4 v = ((const float4*)src)[j];
    u32 lo = (u32)f2bf(v.x) | ((u32)f2bf(v.y) << 16);
    u32 hi = (u32)f2bf(v.z) | ((u32)f2bf(v.w) << 16);
    ((uint2*)dst)[j] = make_uint2(lo, hi);
}

// ============ GEMM core v3 (R3 exact): single-barrier dbuf + XCD supertile ==
// Session ledger: 128^2 tile @2 blk/CU -23us; 3-deep BK=32 counted-vmcnt
// -23us; MFMA setprio ~null; direct-from-L2 frag loads (flash) -119us;
// fused z-cvt staging -18us. Residency (3 blk/CU) + simple single-barrier
// loop + XCD A-slice locality is the verified local optimum.
#define GEMM_CORE(Xp, Wp, TM, SMELEMS)                                         \
    __shared__ u16 smem[SMELEMS];                                              \
    u16* ldsA = smem;                 /* [2][TM*BK] */                         \
    u16* ldsB = smem + 2 * (TM) * BK; /* [2][128*BK] */                        \
    const int tid = threadIdx.x;                                               \
    const int wave = tid >> 6, lane = tid & 63;                                \
    const int lrow = lane & 15, quad = lane >> 4;                              \
    const int flat_ = blockIdx.x;                                              \
    const int mbase = (((flat_ & 7) << 4) | ((flat_ >> 3) & 15)) * (TM);       \
    const int nbase = (flat_ >> 7) * 128;                                      \
    const int srow = tid >> 3;      /* 0..31 */                                \
    const int schunk = tid & 7;                                                \
    const int sk = (schunk ^ (srow & 7)) << 3; /* swizzled global k-offset */  \
    const int sdst = srow * BK + schunk * 8;   /* lane-contiguous LDS dest */  \
    const u16* gA = Xp + (size_t)(mbase + srow) * D_ + sk;                     \
    const u16* gB = Wp + (size_t)(nbase + srow) * D_ + sk;                     \
    const int m_ofs = (wave >> 1) * ((TM) / 2);                                \
    const int n_ofs = (wave & 1) * 64;                                         \
    const int e_ = lrow & 7;                                                   \
    const int offA0 = (m_ofs + lrow) * BK + ((quad ^ e_) << 3);                \
    const int offB0 = (n_ofs + lrow) * BK + ((quad ^ e_) << 3);                \
    f32x4 acc[(TM) / 32][4] = {};                                              \
    _Pragma("unroll") for (int i = 0; i < (TM) / 32; i++)                      \
        g2l16(gA + (size_t)(32 * i) * D_, ldsA + sdst + i * 32 * BK);          \
    _Pragma("unroll") for (int i = 0; i < 4; i++)                              \
        g2l16(gB + (size_t)(32 * i) * D_, ldsB + sdst + i * 32 * BK);          \
    for (int it = 0; it < D_ / BK; it++) {                                     \
        const int cur = it & 1;                                                \
        const int abase = cur * (TM) * BK, bbase = cur * 128 * BK;             \
        __syncthreads(); /* drains DMA for buf[cur]; compute of cur^1 done */  \
        if (it + 1 < D_ / BK) {                                                \
            const int kt2 = (it + 1) * BK;                                     \
            const int nb = cur ^ 1;                                            \
            _Pragma("unroll") for (int i = 0; i < (TM) / 32; i++)              \
                g2l16(gA + (size_t)(32 * i) * D_ + kt2,                        \
                      ldsA + nb * (TM) * BK + sdst + i * 32 * BK);             \
            _Pragma("unroll") for (int i = 0; i < 4; i++)                      \
                g2l16(gB + (size_t)(32 * i) * D_ + kt2,                        \
                      ldsB + nb * 128 * BK + sdst + i * 32 * BK);              \
        }                                                                      \
        _Pragma("unroll") for (int ks = 0; ks < 2; ks++) {                     \
            const int oa = abase + (offA0 ^ (ks << 5));                       \
            const int ob = bbase + (offB0 ^ (ks << 5));                       \
            bf16x8 af[(TM) / 32], bfr[4];                                      \
            _Pragma("unroll") for (int c = 0; c < (TM) / 32; c++)              \
                af[c] = *(const bf16x8*)&ldsA[oa + c * 16 * BK];               \
            _Pragma("unroll") for (int c = 0; c < 4; c++)                      \
                bfr[c] = *(const bf16x8*)&ldsB[ob + c * 16 * BK];              \
            _Pragma("unroll") for (int i = 0; i < (TM) / 32; i++)              \
                _Pragma("unroll") for (int j = 0; j < 4; j++)                  \
                    acc[i][j] = mfma16(af[i], bfr[j], acc[i][j]);              \
        }                                                                      \
    }

// ---------------- QKV projection GEMM (64x128 tile, grid 2304 = 9/CU) -------
__global__ __launch_bounds__(256) void gemm_qkv(const u16* __restrict__ X,
                                                const u16* __restrict__ W,
                                                const float* __restrict__ bqkv,
                                                u16* __restrict__ Qs,
                                                u16* __restrict__ Ks,
                                                u16* __restrict__ Vt) {
    GEMM_CORE(X, W, 64, 24576)
    __syncthreads();  // all waves done reading ldsA/ldsB; smem becomes C-tile
    u16* ldsC = smem;
#pragma unroll
    for (int cn = 0; cn < 4; cn++) {
        const int E = nbase + n_ofs + cn * 16;  // global out-feature base
        const int h = E / 192;
        const int rr = E - h * 192;
        const int kind = rr >> 6;               // 0=Q 1=K 2=V
        const float bias = bqkv[E + lrow];
        if (kind == 2) {
            const int d = (rr & 63) + lrow;
#pragma unroll
            for (int cm = 0; cm < 2; cm++) {
                const int t0 = mbase + m_ofs + cm * 16 + quad * 4;
                const int b_ = t0 >> 11, n0 = t0 & (N_ - 1);
                const size_t bh = (size_t)(b_ * H_ + h);
                uint2 pk;
                pk.x = (u32)f2bf(acc[cm][cn][0] + bias) |
                       ((u32)f2bf(acc[cm][cn][1] + bias) << 16);
                pk.y = (u32)f2bf(acc[cm][cn][2] + bias) |
                       ((u32)f2bf(acc[cm][cn][3] + bias) << 16);
                *(uint2*)&Vt[(bh * HD_ + d) * N_ + n0] = pk;
            }
        } else {
            const int fcol = n_ofs + cn * 16 + lrow;  // block-local feature
            const float scale = (kind == 0) ? QSCALE : 1.0f;
#pragma unroll
            for (int cm = 0; cm < 2; cm++)
#pragma unroll
                for (int r = 0; r < 4; r++) {
                    const int tok = m_ofs + cm * 16 + quad * 4 + r;
                    ldsC[tok * CPITCH + fcol] =
                        f2bf((acc[cm][cn][r] + bias) * scale);
                }
        }
    }
    __syncthreads();
    // store phase: thread -> (token = tid>>2, sub = half(64f) x j-half)
    {
        const int tok = tid >> 2, sub = tid & 3;
        const int fh = sub >> 1, jh = sub & 1;
        const int gf = nbase + fh * 64;          // global feature base of half
        const int kind2 = (gf >> 6) % 3;
        if (kind2 != 2) {
            const int h2 = gf / 192;
            const int t = mbase + tok;
            const int b2 = t >> 11, n2 = t & (N_ - 1);
            u16* dst = (kind2 == 0 ? Qs : Ks) +
                       ((size_t)(b2 * H_ + h2) * N_ + n2) * HD_;
            const u16* src = &ldsC[tok * CPITCH + fh * 64];
#pragma unroll
            for (int j = 0; j < 4; j++)
                *(uint4*)&dst[(jh * 4 + j) * 8] =
                    *(const uint4*)&src[(jh * 4 + j) * 8];
        }
    }
}

// ---------------- output projection GEMM (64x128 tile, 768 blocks) ----------
__global__ __launch_bounds__(256) void gemm_out(const u16* __restrict__ X2,
                                                const u16* __restrict__ W,
                                                const float* __restrict__ bmsa,
                                                float* __restrict__ out) {
    GEMM_CORE(X2, W, 64, 24576)
#pragma unroll
    for (int cn = 0; cn < 4; cn++) {
        const int col = nbase + n_ofs + cn * 16 + lrow;
        const float bias = bmsa[col];
#pragma unroll
        for (int cm = 0; cm < 2; cm++) {
#pragma unroll
            for (int r = 0; r < 4; r++) {
                const int t = mbase + m_ofs + cm * 16 + quad * 4 + r;
                out[(size_t)t * D_ + col] = acc[cm][cn][r] + bias;
            }
        }
    }
}

// -------- Flash attention (R11: V-read hoist + unroll-2 on R3 structure) ----
// R10 recalibration: identical binary measured 197.3 (R3) and 210.4 (R10)
// -> cross-container noise ~±6%; flash-dispatch delta is the reliable
// readout. R11 micro-schedule: (1) hoist the 8 V ds_read_b128 to right
// after the K reads, so their ~120cy LDS latency hides under QK+exp2
// instead of sitting on the PV critical path (V is valid once the barrier
// passes; +32 VGPR, 68->~100 < 168 cap at 3 waves/SIMD). (2) unroll 2:
// 'cur' becomes a literal per body -> LDS offsets fold to immediates.
__global__ __launch_bounds__(256, 3) void flash_attn(const u16* __restrict__ Qs,
                                                     const u16* __restrict__ Ks,
                                                     const u16* __restrict__ Vt,
                                                     u16* __restrict__ X2) {
    __shared__ u16 ldsK[2][64 * HD_];   // 2 x 8 KB
    __shared__ u16 ldsV[2][64 * HD_];   // 2 x 8 KB
    __shared__ u16 ldsP[4][2][16][68];  // row = q (0..15), col = key (0..63)+pad
    const int tid = threadIdx.x;
    const int wave = tid >> 6, lane = tid & 63;
    const int lrow = lane & 15, quad = lane >> 4;
    const int qbase = blockIdx.x * 128 + wave * 32;
    const int bh = blockIdx.y;
    const int b = bh / H_, h = bh - b * H_;

    const u16* Kb = Ks + (size_t)bh * N_ * HD_;
    const u16* Vb = Vt + (size_t)bh * HD_ * N_;

    const int srow = tid >> 3;
    const int schunk = tid & 7;
    const int skk = (schunk ^ (srow & 7)) << 3;
    const int sdst = srow * HD_ + schunk * 8;

    bf16x8 qa[2][2];
#pragma unroll
    for (int t = 0; t < 2; t++) {
        const u16* Qb = Qs + ((size_t)bh * N_ + qbase + t * 16 + lrow) * HD_ + quad * 8;
        qa[t][0] = *(const bf16x8*)(Qb);
        qa[t][1] = *(const bf16x8*)(Qb + 32);
    }

    const int fofs = (quad ^ (lrow & 7)) << 3;
    const short onebf = (short)0x3F80;  // bf16 1.0
    const bf16x8 ones = {onebf, onebf, onebf, onebf, onebf, onebf, onebf, onebf};

    f32x4 Oacc[2][4] = {};
    f32x4 lacc[2] = {};

    {   // prologue: stage tile 0 into buffer 0
        const u16* gK = Kb + (size_t)srow * HD_ + skk;
        g2l16(gK, &ldsK[0][sdst]);
        g2l16(gK + (size_t)32 * HD_, &ldsK[0][sdst + 32 * HD_]);
        const u16* gV = Vb + (size_t)srow * N_ + skk;
        g2l16(gV, &ldsV[0][sdst]);
        g2l16(gV + (size_t)32 * N_, &ldsV[0][sdst + 32 * HD_]);
    }

#pragma unroll 2
    for (int it = 0; it < N_ / 64; it++) {
        const int cur = it & 1;
        __syncthreads();  // drains DMA for buf[cur]; waves done with buf[cur^1]
        if (it + 1 < N_ / 64) {
            const int kt2 = (it + 1) << 6;
            const u16* gK = Kb + (size_t)(kt2 + srow) * HD_ + skk;
            g2l16(gK, &ldsK[cur ^ 1][sdst]);
            g2l16(gK + (size_t)32 * HD_, &ldsK[cur ^ 1][sdst + 32 * HD_]);
            const u16* gV = Vb + (size_t)srow * N_ + kt2 + skk;
            g2l16(gV, &ldsV[cur ^ 1][sdst]);
            g2l16(gV + (size_t)32 * N_, &ldsV[cur ^ 1][sdst + 32 * HD_]);
        }
        // ---- K fragments from LDS (A-operand: A[m=key][k=d]) ----
        bf16x8 kf[8];
#pragma unroll
        for (int c = 0; c < 4; c++) {
            const int o = (c * 16 + lrow) * HD_ + fofs;
            kf[2 * c]     = *(const bf16x8*)&ldsK[cur][o];
            kf[2 * c + 1] = *(const bf16x8*)&ldsK[cur][o ^ 32];
        }
        // ---- V fragments hoisted: issue now, latency hides under QK+exp2 ----
        bf16x8 vf[8];
#pragma unroll
        for (int c = 0; c < 4; c++) {
            const int o = (c * 16 + lrow) * HD_ + fofs;
            vf[2 * c]     = *(const bf16x8*)&ldsV[cur][o];
            vf[2 * c + 1] = *(const bf16x8*)&ldsV[cur][o ^ 32];
        }
        // ---- S^T = K Q^T : lane holds (key=c*16+quad*4+r, q=lrow) ----
        f32x4 s[2][4] = {};
        __builtin_amdgcn_s_setprio(1);
#pragma unroll
        for (int t = 0; t < 2; t++)
#pragma unroll
            for (int c = 0; c < 4; c++) {
                s[t][c] = mfma16(kf[2 * c], qa[t][0], s[t][c]);
                s[t][c] = mfma16(kf[2 * c + 1], qa[t][1], s[t][c]);
            }
        __builtin_amdgcn_s_setprio(0);
        // ---- P = 2^S (raw v_exp_f32), truncate-pack pairs -> b64 store ----
        // (truncation bias cancels: l sums the same truncated bf16 P)
#pragma unroll
        for (int t = 0; t < 2; t++)
#pragma unroll
            for (int c = 0; c < 4; c++) {
                u32 b0 = __float_as_uint(__builtin_amdgcn_exp2f(s[t][c][0]));
                u32 b1 = __float_as_uint(__builtin_amdgcn_exp2f(s[t][c][1]));
                u32 b2 = __float_as_uint(__builtin_amdgcn_exp2f(s[t][c][2]));
                u32 b3 = __float_as_uint(__builtin_amdgcn_exp2f(s[t][c][3]));
                uint2 pk;
                pk.x = __builtin_amdgcn_perm(b1, b0, 0x07060302u);
                pk.y = __builtin_amdgcn_perm(b3, b2, 0x07060302u);
                *(uint2*)&ldsP[wave][t][lrow][c * 16 + quad * 4] = pk;
            }
        bf16x8 pa[2][2];
#pragma unroll
        for (int t = 0; t < 2; t++) {
            pa[t][0] = *(const bf16x8*)&ldsP[wave][t][lrow][quad * 8];
            pa[t][1] = *(const bf16x8*)&ldsP[wave][t][lrow][32 + quad * 8];
        }
        // ---- row sums via MFMA + O += P V (one prio-1 MFMA cluster) ----
        __builtin_amdgcn_s_setprio(1);
#pragma unroll
        for (int t = 0; t < 2; t++) {
            lacc[t] = mfma16(pa[t][0], ones, lacc[t]);
            lacc[t] = mfma16(pa[t][1], ones, lacc[t]);
        }
#pragma unroll
        for (int c = 0; c < 4; c++) {
#pragma unroll
            for (int t = 0; t < 2; t++) {
                Oacc[t][c] = mfma16(pa[t][0], vf[2 * c], Oacc[t][c]);
                Oacc[t][c] = mfma16(pa[t][1], vf[2 * c + 1], Oacc[t][c]);
            }
        }
        __builtin_amdgcn_s_setprio(0);
    }
    // ---- epilogue: lacc[t][r] is the row sum (row = quad*4+r) ----
#pragma unroll
    for (int t = 0; t < 2; t++)
#pragma unroll
        for (int r = 0; r < 4; r++) {
            const float inv = 1.0f / lacc[t][r];
            const int qrow = qbase + t * 16 + quad * 4 + r;
#pragma unroll
            for (int c = 0; c < 4; c++) {
                X2[((size_t)b * N_ + qrow) * D_ + h * HD_ + c * 16 + lrow] =
                    f2bf(Oacc[t][c][r] * inv);
            }
        }
}

extern "C" void kernel_launch(void* const* d_in, const int* in_sizes, int n_in,
                              void* d_out, int out_size, void* d_ws, size_t ws_size,
                              hipStream_t stream) {
    const float* z    = (const float*)d_in[0];
    const float* Wqkv = (const float*)d_in[1];
    const float* bqkv = (const float*)d_in[2];
    const float* Wmsa = (const float*)d_in[3];
    const float* bmsa = (const float*)d_in[4];
    float* out = (float*)d_out;

    u16* Xbf = (u16*)d_ws;
    u16* Wqb = Xbf + (size_t)NTOK * D_;
    u16* Wmb = Wqb + (size_t)NE * D_;
    u16* Qs  = Wmb + (size_t)D_ * D_;
    u16* Ks  = Qs + (size_t)B_ * H_ * N_ * HD_;
    u16* Vt  = Ks + (size_t)B_ * H_ * N_ * HD_;
    u16* X2  = Vt + (size_t)B_ * H_ * N_ * HD_;

    const int ntot = NZ4 + NWQ4 + NWM4;
    cvt_all<<<(ntot + 255) / 256, 256, 0, stream>>>(z, Wqkv, Wmsa, Xbf, Wqb, Wmb);

    // 1D grids; GEMM_CORE decodes XCD-supertile (x,y) from blockIdx.x.
    gemm_qkv<<<dim3((NTOK / 64) * (NE / 128)), 256, 0, stream>>>(Xbf, Wqb, bqkv, Qs, Ks, Vt);
    flash_attn<<<dim3(N_ / 128, B_ * H_), 256, 0, stream>>>(Qs, Ks, Vt, X2);
    gemm_out<<<dim3((NTOK / 64) * (D_ / 128)), 256, 0, stream>>>(X2, Wmb, bmsa, out);
}